// Round 10
// baseline (201.325 us; speedup 1.0000x reference)
//
#include <hip/hip_runtime.h>

#define B_   4
#define S_   4096
#define NC   8192
#define C_   512
#define CS   256
#define KTOT 768

typedef __attribute__((ext_vector_type(8))) short short8;
typedef __attribute__((ext_vector_type(4))) float f32x4;

// fp32 -> bf16 round-to-nearest-even (finite inputs only)
static __device__ __forceinline__ unsigned short f2bf(float x) {
    unsigned u = __builtin_bit_cast(unsigned, x);
    unsigned r = u + 0x7FFFu + ((u >> 16) & 1u);
    return (unsigned short)(r >> 16);
}

// ================= K1: fused prep (R8 verbatim, 288 blocks) =================
// bid 0..63: beff | 64..95: wc | 96..159: w1 | 160..287: pad_ref
__global__ __launch_bounds__(256) void prep_kernel(
        const float* __restrict__ rxyz, float4* __restrict__ refpk,
        const float* __restrict__ Wcat, const float* __restrict__ Wseed,
        unsigned short* __restrict__ Wcomb,
        const float* __restrict__ bseed, const float* __restrict__ bcat,
        float* __restrict__ beff) {
    __shared__ float sa[64][68];
    __shared__ float sbt[64][68];
    int bid = blockIdx.x;
    int tid = threadIdx.x;

    if (bid < 64) {
        int w = tid >> 6, l = tid & 63;
        int o = bid * 4 + w;
        float4 wv = *(const float4*)(Wcat + (size_t)o * 512 + 256 + l * 4);
        float4 bb = *(const float4*)(bseed + l * 4);
        float acc = __fmul_rn(wv.x, bb.x);
        acc = fmaf(wv.y, bb.y, acc);
        acc = fmaf(wv.z, bb.z, acc);
        acc = fmaf(wv.w, bb.w, acc);
        #pragma unroll
        for (int off = 32; off > 0; off >>= 1) acc += __shfl_down(acc, off);
        if (l == 0) beff[o] = acc + bcat[o];
    } else if (bid < 96) {
        int xb = bid - 64;
        int tc = (xb & 7) * 64;
        int to = (xb >> 3) * 64;
        int tx = tid & 15, ty = tid >> 4;
        float acc[4][4] = {};
        for (int kt = 0; kt < 256; kt += 64) {
            __syncthreads();
            #pragma unroll
            for (int r = 0; r < 4; ++r) {
                int oo = r * 16 + ty;
                float4 v = *(const float4*)(Wcat + (size_t)(to + oo) * 512 + 256 + kt + tx * 4);
                sa[oo][tx * 4 + 0] = v.x;
                sa[oo][tx * 4 + 1] = v.y;
                sa[oo][tx * 4 + 2] = v.z;
                sa[oo][tx * 4 + 3] = v.w;
                float4 u = *(const float4*)(Wseed + (size_t)(kt + oo) * 512 + tc + tx * 4);
                sbt[oo][tx * 4 + 0] = u.x;
                sbt[oo][tx * 4 + 1] = u.y;
                sbt[oo][tx * 4 + 2] = u.z;
                sbt[oo][tx * 4 + 3] = u.w;
            }
            __syncthreads();
            for (int k = 0; k < 64; ++k) {
                float a[4], bb2[4];
                #pragma unroll
                for (int i = 0; i < 4; ++i) a[i] = sa[ty * 4 + i][k];
                #pragma unroll
                for (int j = 0; j < 4; ++j) bb2[j] = sbt[k][tx * 4 + j];
                #pragma unroll
                for (int i = 0; i < 4; ++i)
                    #pragma unroll
                    for (int j = 0; j < 4; ++j)
                        acc[i][j] = fmaf(a[i], bb2[j], acc[i][j]);
            }
        }
        #pragma unroll
        for (int i = 0; i < 4; ++i)
            #pragma unroll
            for (int j = 0; j < 4; ++j)
                Wcomb[(size_t)(to + ty * 4 + i) * KTOT + 256 + tc + tx * 4 + j] = f2bf(acc[i][j]);
    } else if (bid < 160) {
        int g = ((bid - 96) * 256 + tid) * 4;
        int o = g >> 8, cc = g & 255;
        float4 v = *(const float4*)(Wcat + (size_t)o * 512 + cc);
        ushort4 ov;
        ov.x = f2bf(v.x); ov.y = f2bf(v.y); ov.z = f2bf(v.z); ov.w = f2bf(v.w);
        *(ushort4*)(Wcomb + (size_t)o * KTOT + cc) = ov;
    } else {
        int gid = (bid - 160) * 256 + tid;  // 0..32767
        float x = rxyz[gid * 3 + 0];
        float y = rxyz[gid * 3 + 1];
        float z = rxyz[gid * 3 + 2];
        float r2 = __fadd_rn(__fadd_rn(__fmul_rn(x, x), __fmul_rn(y, y)), __fmul_rn(z, z));
        refpk[gid] = make_float4(x, y, z, r2);
    }
}

// ================= K2: fused argmin + refT transpose + seedT transpose (R8 verbatim) =================
// 7168 blocks, residue mod 7: {0,4} -> argmin (2048), {1,2,3,5} -> refT
// transpose (4096), {6} -> seedT transpose (1024).
__global__ __launch_bounds__(256, 4) void mid_kernel(
        const float* __restrict__ qxyz, const float4* __restrict__ refpk,
        float* __restrict__ pval, int* __restrict__ pidx,
        const float* __restrict__ rf, unsigned short* __restrict__ refT,
        const float* __restrict__ seed, unsigned short* __restrict__ seedT) {
    __shared__ float t[64][65];
    int bid = blockIdx.x;
    int tid = threadIdx.x;
    int r7 = bid % 7;
    int g7 = bid / 7;                      // 0..1023

    if (r7 == 0 || r7 == 4) {
        // ---------- argmin path: one 2048-ref chunk, 32 queries/block ----------
        int aid = g7 * 2 + (r7 == 4);      // 0..2047
        int sblk = aid & 127;
        int c = (aid >> 7) & 3;
        int b = aid >> 9;
        int lane = tid & 63;
        int qg = tid >> 6;
        int sbase = sblk * 32 + qg * 8;

        float qx[8], qy[8], qz[8], q2[8];
        #pragma unroll
        for (int q = 0; q < 8; ++q) {
            const float* qp = qxyz + ((size_t)(b * S_ + sbase + q)) * 3;
            qx[q] = qp[0]; qy[q] = qp[1]; qz[q] = qp[2];
            q2[q] = __fadd_rn(__fadd_rn(__fmul_rn(qx[q], qx[q]), __fmul_rn(qy[q], qy[q])),
                              __fmul_rn(qz[q], qz[q]));
        }

        const float4* ep = refpk + (size_t)b * NC + c * 2048 + lane;
        float best[8];
        int bj[8];
        #pragma unroll
        for (int q = 0; q < 8; ++q) { best[q] = 3.4028235e38f; bj[q] = 0; }

        // 2-deep software prefetch; processing order stays ascending.
        float4 r0 = ep[0];
        float4 r1 = ep[64];
        #pragma unroll 2
        for (int j = 0; j < 32; j += 2) {
            float4 r2 = r0, r3 = r1;
            if (j + 2 < 32) {
                r2 = ep[(j + 2) * 64];
                r3 = ep[(j + 3) * 64];
            }
            #pragma unroll
            for (int q = 0; q < 8; ++q) {
                // qr = ((qx*rx + qy*ry) + qz*rz), no FMA (np association)
                float qr = __fadd_rn(__fadd_rn(__fmul_rn(qx[q], r0.x), __fmul_rn(qy[q], r0.y)),
                                     __fmul_rn(qz[q], r0.z));
                float s = __fadd_rn(q2[q], r0.w);
                float d2 = fmaf(qr, -2.0f, s);   // same single rounding as fsub(s, qr+qr)
                if (d2 < best[q]) { best[q] = d2; bj[q] = j; }
            }
            #pragma unroll
            for (int q = 0; q < 8; ++q) {
                float qr = __fadd_rn(__fadd_rn(__fmul_rn(qx[q], r1.x), __fmul_rn(qy[q], r1.y)),
                                     __fmul_rn(qz[q], r1.z));
                float s = __fadd_rn(q2[q], r1.w);
                float d2 = fmaf(qr, -2.0f, s);
                if (d2 < best[q]) { best[q] = d2; bj[q] = j + 1; }
            }
            r0 = r2;
            r1 = r3;
        }

        int bx[8];
        #pragma unroll
        for (int q = 0; q < 8; ++q) bx[q] = c * 2048 + bj[q] * 64 + lane;

        // In-wave butterfly, (val, idx) lexicographic min = first occurrence.
        #pragma unroll
        for (int m = 1; m < 64; m <<= 1) {
            #pragma unroll
            for (int q = 0; q < 8; ++q) {
                float vv = __shfl_xor(best[q], m, 64);
                int xx = __shfl_xor(bx[q], m, 64);
                if (vv < best[q] || (vv == best[q] && xx < bx[q])) {
                    best[q] = vv; bx[q] = xx;
                }
            }
        }
        if (lane == 0) {
            #pragma unroll
            for (int q = 0; q < 8; ++q) {
                int qs = b * S_ + sbase + q;
                pval[qs * 4 + c] = best[q];
                pidx[qs * 4 + c] = bx[q];
            }
        }
    } else if (r7 != 6) {
        // ---------- refT transpose: (B,C,Nc) fp32 -> (B,Nc,C) bf16 ----------
        int id = g7 * 4 + (r7 - 1 - (r7 > 4 ? 1 : 0));   // 0..4095
        int b = id >> 10;
        int c0 = ((id >> 7) & 7) * 64;
        int n0 = (id & 127) * 64;
        int tx = tid & 15, ty = tid >> 4;
        #pragma unroll
        for (int r = 0; r < 4; ++r) {
            int cc = r * 16 + ty;
            float4 v = *(const float4*)(rf + ((size_t)b * C_ + c0 + cc) * NC + n0 + tx * 4);
            t[tx * 4 + 0][cc] = v.x;
            t[tx * 4 + 1][cc] = v.y;
            t[tx * 4 + 2][cc] = v.z;
            t[tx * 4 + 3][cc] = v.w;
        }
        __syncthreads();
        #pragma unroll
        for (int r = 0; r < 4; ++r) {
            int n = r * 16 + ty;
            ushort4 o;
            o.x = f2bf(t[n][tx * 4 + 0]);
            o.y = f2bf(t[n][tx * 4 + 1]);
            o.z = f2bf(t[n][tx * 4 + 2]);
            o.w = f2bf(t[n][tx * 4 + 3]);
            *(ushort4*)(refT + ((size_t)b * NC + n0 + n) * C_ + c0 + tx * 4) = o;
        }
    } else {
        // ---------- seedT transpose: (B,CS,S) fp32 -> (B,S,CS) bf16 ----------
        int id = g7;                       // 0..1023
        int b = id >> 8;
        int rem = id & 255;
        int c0 = (rem >> 6) * 64;          // 0..192
        int s0 = (rem & 63) * 64;          // 0..4032
        int tx = tid & 15, ty = tid >> 4;
        #pragma unroll
        for (int r = 0; r < 4; ++r) {
            int cc = r * 16 + ty;
            float4 v = *(const float4*)(seed + ((size_t)b * CS + c0 + cc) * S_ + s0 + tx * 4);
            t[tx * 4 + 0][cc] = v.x;
            t[tx * 4 + 1][cc] = v.y;
            t[tx * 4 + 2][cc] = v.z;
            t[tx * 4 + 3][cc] = v.w;
        }
        __syncthreads();
        #pragma unroll
        for (int r = 0; r < 4; ++r) {
            int n = r * 16 + ty;
            ushort4 o;
            o.x = f2bf(t[n][tx * 4 + 0]);
            o.y = f2bf(t[n][tx * 4 + 1]);
            o.z = f2bf(t[n][tx * 4 + 2]);
            o.w = f2bf(t[n][tx * 4 + 3]);
            *(ushort4*)(seedT + ((size_t)b * S_ + s0 + n) * CS + c0 + tx * 4) = o;
        }
    }
}

// ================= K3: fused merge + gather + GEMM, LDS-free direct-MFMA =================
// out[b](256 x 4096) = Wcomb(256x768) @ [seedT^T; gathered refT^T] + b_eff
// Tile 64x128, 2x2 waves owning 32x64 each. Every MFMA fragment is one
// aligned 16B per-lane global load (no cross-lane sharing needed), so LDS
// staging + all 12 K-loop barriers are DELETED: the unrolled loop is pure
// dataflow (6 loads + 8 MFMA per kf-step) the compiler can pipeline deep.
// Cost: 2x fragment read amplification, all L1/L2-cached (Wcomb 384KB,
// B rows reused by 2 waves). Fragment values and MFMA order (ks,kf,i,j)
// identical to R9 -> bit-identical output.
__global__ __launch_bounds__(256) void fused_gemm_kernel(
        const unsigned short* __restrict__ Wcomb,
        const unsigned short* __restrict__ seedT,
        const unsigned short* __restrict__ refT,
        const float* __restrict__ pval,
        const int* __restrict__ pidx,
        const float* __restrict__ beff,
        float* __restrict__ out) {
    __shared__ int sIdx[128];
    __shared__ float sBias[64];

    int tid = threadIdx.x;
    int b = blockIdx.z;
    int m0 = blockIdx.y * 64;
    int s0 = blockIdx.x * 128;
    if (tid < 128) {
        // merge 4 chunk-partials; disjoint ascending index ranges -> (val,idx) min
        int qs = b * S_ + s0 + tid;
        float v = pval[qs * 4 + 0];
        int x = pidx[qs * 4 + 0];
        #pragma unroll
        for (int c = 1; c < 4; ++c) {
            float vv = pval[qs * 4 + c];
            int xx = pidx[qs * 4 + c];
            if (vv < v || (vv == v && xx < x)) { v = vv; x = xx; }
        }
        sIdx[tid] = x & (NC - 1);   // defensive clamp
        if (tid < 64) sBias[tid] = beff[m0 + tid];
    }
    __syncthreads();

    int lane = tid & 63;
    int w = tid >> 6;
    int wm = w >> 1;                // 0..1  (M half)
    int wn = w & 1;                 // 0..1  (N half)
    int ln = lane & 15;
    int quad = lane >> 4;
    int q8 = quad * 8;

    // Per-lane fragment base pointers (resolved once; gather rows via sIdx).
    const unsigned short* Abase[2];
    #pragma unroll
    for (int i = 0; i < 2; ++i)
        Abase[i] = Wcomb + (size_t)(m0 + wm * 32 + i * 16 + ln) * KTOT + q8;
    const unsigned short* Sbase[4];
    const unsigned short* Gbase[4];
    #pragma unroll
    for (int j = 0; j < 4; ++j) {
        int row = wn * 64 + j * 16 + ln;
        Sbase[j] = seedT + ((size_t)b * S_ + s0 + row) * CS + q8;
        Gbase[j] = refT + ((size_t)b * NC + sIdx[row]) * C_ + q8;
    }

    f32x4 acc[2][4];
    #pragma unroll
    for (int i = 0; i < 2; ++i)
        #pragma unroll
        for (int j = 0; j < 4; ++j)
            acc[i][j] = (f32x4){0.f, 0.f, 0.f, 0.f};

    #pragma unroll
    for (int ks = 0; ks < 12; ++ks) {
        #pragma unroll
        for (int kf = 0; kf < 2; ++kf) {
            int k = ks * 64 + kf * 32;      // compile-time after unroll
            short8 af[2], bfr[4];
            #pragma unroll
            for (int i = 0; i < 2; ++i)
                af[i] = *(const short8*)(Abase[i] + k);
            if (k < 256) {
                #pragma unroll
                for (int j = 0; j < 4; ++j)
                    bfr[j] = *(const short8*)(Sbase[j] + k);
            } else {
                #pragma unroll
                for (int j = 0; j < 4; ++j)
                    bfr[j] = *(const short8*)(Gbase[j] + (k - 256));
            }
            #pragma unroll
            for (int i = 0; i < 2; ++i)
                #pragma unroll
                for (int j = 0; j < 4; ++j)
                    acc[i][j] = __builtin_amdgcn_mfma_f32_16x16x32_bf16(af[i], bfr[j], acc[i][j], 0, 0, 0);
        }
    }

    #pragma unroll
    for (int i = 0; i < 2; ++i) {
        int mb = wm * 32 + i * 16 + quad * 4;
        #pragma unroll
        for (int j = 0; j < 4; ++j) {
            int col = s0 + wn * 64 + j * 16 + ln;
            #pragma unroll
            for (int r = 0; r < 4; ++r) {
                int m = mb + r;
                out[((size_t)b * CS + m0 + m) * S_ + col] = acc[i][j][r] + sBias[m];
            }
        }
    }
}

extern "C" void kernel_launch(void* const* d_in, const int* in_sizes, int n_in,
                              void* d_out, int out_size, void* d_ws, size_t ws_size,
                              hipStream_t stream) {
    const float* qxyz  = (const float*)d_in[0];
    const float* rxyz  = (const float*)d_in[1];
    const float* rfeat = (const float*)d_in[2];
    const float* seed  = (const float*)d_in[3];
    const float* Wseed = (const float*)d_in[4];
    const float* bseed = (const float*)d_in[5];
    const float* Wcat  = (const float*)d_in[6];
    const float* bcat  = (const float*)d_in[7];
    float* out = (float*)d_out;

    char* ws = (char*)d_ws;
    float* pval           = (float*)(ws);                        // 256 KB
    int* pidx             = (int*)(ws + 262144);                 // 256 KB
    float* beff           = (float*)(ws + 524288);               // 1 KB
    float4* refpk         = (float4*)(ws + 528384);              // 512 KB
    unsigned short* Wcomb = (unsigned short*)(ws + 1052672);     // 384 KB
    unsigned short* refT  = (unsigned short*)(ws + 1445888);     // 32 MB -> 35000320
    unsigned short* seedT = (unsigned short*)(ws + 35000320);    // 8 MB  -> end 43.4 MB

    hipLaunchKernelGGL(prep_kernel, dim3(288), dim3(256), 0, stream,
                       rxyz, refpk, Wcat, Wseed, Wcomb, bseed, bcat, beff);
    hipLaunchKernelGGL(mid_kernel, dim3(7168), dim3(256), 0, stream,
                       qxyz, refpk, pval, pidx, rfeat, refT, seed, seedT);
    hipLaunchKernelGGL(fused_gemm_kernel, dim3(32, 4, 4), dim3(256), 0, stream,
                       Wcomb, seedT, refT, pval, pidx, beff, out);
}

// Round 11
// 181.360 us; speedup vs baseline: 1.1101x; 1.1101x over previous
//
#include <hip/hip_runtime.h>

#define B_   4
#define S_   4096
#define NC   8192
#define C_   512
#define CS   256
#define KTOT 768

typedef __attribute__((ext_vector_type(8))) short short8;
typedef __attribute__((ext_vector_type(4))) float f32x4;

// fp32 -> bf16 round-to-nearest-even (finite inputs only)
static __device__ __forceinline__ unsigned short f2bf(float x) {
    unsigned u = __builtin_bit_cast(unsigned, x);
    unsigned r = u + 0x7FFFu + ((u >> 16) & 1u);
    return (unsigned short)(r >> 16);
}

// ================= K1: fused prep (R8 verbatim, 288 blocks) =================
// bid 0..63: beff | 64..95: wc | 96..159: w1 | 160..287: pad_ref
__global__ __launch_bounds__(256) void prep_kernel(
        const float* __restrict__ rxyz, float4* __restrict__ refpk,
        const float* __restrict__ Wcat, const float* __restrict__ Wseed,
        unsigned short* __restrict__ Wcomb,
        const float* __restrict__ bseed, const float* __restrict__ bcat,
        float* __restrict__ beff) {
    __shared__ float sa[64][68];
    __shared__ float sbt[64][68];
    int bid = blockIdx.x;
    int tid = threadIdx.x;

    if (bid < 64) {
        int w = tid >> 6, l = tid & 63;
        int o = bid * 4 + w;
        float4 wv = *(const float4*)(Wcat + (size_t)o * 512 + 256 + l * 4);
        float4 bb = *(const float4*)(bseed + l * 4);
        float acc = __fmul_rn(wv.x, bb.x);
        acc = fmaf(wv.y, bb.y, acc);
        acc = fmaf(wv.z, bb.z, acc);
        acc = fmaf(wv.w, bb.w, acc);
        #pragma unroll
        for (int off = 32; off > 0; off >>= 1) acc += __shfl_down(acc, off);
        if (l == 0) beff[o] = acc + bcat[o];
    } else if (bid < 96) {
        int xb = bid - 64;
        int tc = (xb & 7) * 64;
        int to = (xb >> 3) * 64;
        int tx = tid & 15, ty = tid >> 4;
        float acc[4][4] = {};
        for (int kt = 0; kt < 256; kt += 64) {
            __syncthreads();
            #pragma unroll
            for (int r = 0; r < 4; ++r) {
                int oo = r * 16 + ty;
                float4 v = *(const float4*)(Wcat + (size_t)(to + oo) * 512 + 256 + kt + tx * 4);
                sa[oo][tx * 4 + 0] = v.x;
                sa[oo][tx * 4 + 1] = v.y;
                sa[oo][tx * 4 + 2] = v.z;
                sa[oo][tx * 4 + 3] = v.w;
                float4 u = *(const float4*)(Wseed + (size_t)(kt + oo) * 512 + tc + tx * 4);
                sbt[oo][tx * 4 + 0] = u.x;
                sbt[oo][tx * 4 + 1] = u.y;
                sbt[oo][tx * 4 + 2] = u.z;
                sbt[oo][tx * 4 + 3] = u.w;
            }
            __syncthreads();
            for (int k = 0; k < 64; ++k) {
                float a[4], bb2[4];
                #pragma unroll
                for (int i = 0; i < 4; ++i) a[i] = sa[ty * 4 + i][k];
                #pragma unroll
                for (int j = 0; j < 4; ++j) bb2[j] = sbt[k][tx * 4 + j];
                #pragma unroll
                for (int i = 0; i < 4; ++i)
                    #pragma unroll
                    for (int j = 0; j < 4; ++j)
                        acc[i][j] = fmaf(a[i], bb2[j], acc[i][j]);
            }
        }
        #pragma unroll
        for (int i = 0; i < 4; ++i)
            #pragma unroll
            for (int j = 0; j < 4; ++j)
                Wcomb[(size_t)(to + ty * 4 + i) * KTOT + 256 + tc + tx * 4 + j] = f2bf(acc[i][j]);
    } else if (bid < 160) {
        int g = ((bid - 96) * 256 + tid) * 4;
        int o = g >> 8, cc = g & 255;
        float4 v = *(const float4*)(Wcat + (size_t)o * 512 + cc);
        ushort4 ov;
        ov.x = f2bf(v.x); ov.y = f2bf(v.y); ov.z = f2bf(v.z); ov.w = f2bf(v.w);
        *(ushort4*)(Wcomb + (size_t)o * KTOT + cc) = ov;
    } else {
        int gid = (bid - 160) * 256 + tid;  // 0..32767
        float x = rxyz[gid * 3 + 0];
        float y = rxyz[gid * 3 + 1];
        float z = rxyz[gid * 3 + 2];
        float r2 = __fadd_rn(__fadd_rn(__fmul_rn(x, x), __fmul_rn(y, y)), __fmul_rn(z, z));
        refpk[gid] = make_float4(x, y, z, r2);
    }
}

// ================= K2: fused argmin + refT transpose + seedT transpose (R8 verbatim) =================
// 7168 blocks, residue mod 7: {0,4} -> argmin (2048), {1,2,3,5} -> refT
// transpose (4096), {6} -> seedT transpose (1024).
__global__ __launch_bounds__(256, 4) void mid_kernel(
        const float* __restrict__ qxyz, const float4* __restrict__ refpk,
        float* __restrict__ pval, int* __restrict__ pidx,
        const float* __restrict__ rf, unsigned short* __restrict__ refT,
        const float* __restrict__ seed, unsigned short* __restrict__ seedT) {
    __shared__ float t[64][65];
    int bid = blockIdx.x;
    int tid = threadIdx.x;
    int r7 = bid % 7;
    int g7 = bid / 7;                      // 0..1023

    if (r7 == 0 || r7 == 4) {
        // ---------- argmin path: one 2048-ref chunk, 32 queries/block ----------
        int aid = g7 * 2 + (r7 == 4);      // 0..2047
        int sblk = aid & 127;
        int c = (aid >> 7) & 3;
        int b = aid >> 9;
        int lane = tid & 63;
        int qg = tid >> 6;
        int sbase = sblk * 32 + qg * 8;

        float qx[8], qy[8], qz[8], q2[8];
        #pragma unroll
        for (int q = 0; q < 8; ++q) {
            const float* qp = qxyz + ((size_t)(b * S_ + sbase + q)) * 3;
            qx[q] = qp[0]; qy[q] = qp[1]; qz[q] = qp[2];
            q2[q] = __fadd_rn(__fadd_rn(__fmul_rn(qx[q], qx[q]), __fmul_rn(qy[q], qy[q])),
                              __fmul_rn(qz[q], qz[q]));
        }

        const float4* ep = refpk + (size_t)b * NC + c * 2048 + lane;
        float best[8];
        int bj[8];
        #pragma unroll
        for (int q = 0; q < 8; ++q) { best[q] = 3.4028235e38f; bj[q] = 0; }

        // 2-deep software prefetch; processing order stays ascending.
        float4 r0 = ep[0];
        float4 r1 = ep[64];
        #pragma unroll 2
        for (int j = 0; j < 32; j += 2) {
            float4 r2 = r0, r3 = r1;
            if (j + 2 < 32) {
                r2 = ep[(j + 2) * 64];
                r3 = ep[(j + 3) * 64];
            }
            #pragma unroll
            for (int q = 0; q < 8; ++q) {
                // qr = ((qx*rx + qy*ry) + qz*rz), no FMA (np association)
                float qr = __fadd_rn(__fadd_rn(__fmul_rn(qx[q], r0.x), __fmul_rn(qy[q], r0.y)),
                                     __fmul_rn(qz[q], r0.z));
                float s = __fadd_rn(q2[q], r0.w);
                float d2 = fmaf(qr, -2.0f, s);   // same single rounding as fsub(s, qr+qr)
                if (d2 < best[q]) { best[q] = d2; bj[q] = j; }
            }
            #pragma unroll
            for (int q = 0; q < 8; ++q) {
                float qr = __fadd_rn(__fadd_rn(__fmul_rn(qx[q], r1.x), __fmul_rn(qy[q], r1.y)),
                                     __fmul_rn(qz[q], r1.z));
                float s = __fadd_rn(q2[q], r1.w);
                float d2 = fmaf(qr, -2.0f, s);
                if (d2 < best[q]) { best[q] = d2; bj[q] = j + 1; }
            }
            r0 = r2;
            r1 = r3;
        }

        int bx[8];
        #pragma unroll
        for (int q = 0; q < 8; ++q) bx[q] = c * 2048 + bj[q] * 64 + lane;

        // In-wave butterfly, (val, idx) lexicographic min = first occurrence.
        #pragma unroll
        for (int m = 1; m < 64; m <<= 1) {
            #pragma unroll
            for (int q = 0; q < 8; ++q) {
                float vv = __shfl_xor(best[q], m, 64);
                int xx = __shfl_xor(bx[q], m, 64);
                if (vv < best[q] || (vv == best[q] && xx < bx[q])) {
                    best[q] = vv; bx[q] = xx;
                }
            }
        }
        if (lane == 0) {
            #pragma unroll
            for (int q = 0; q < 8; ++q) {
                int qs = b * S_ + sbase + q;
                pval[qs * 4 + c] = best[q];
                pidx[qs * 4 + c] = bx[q];
            }
        }
    } else if (r7 != 6) {
        // ---------- refT transpose: (B,C,Nc) fp32 -> (B,Nc,C) bf16 ----------
        int id = g7 * 4 + (r7 - 1 - (r7 > 4 ? 1 : 0));   // 0..4095
        int b = id >> 10;
        int c0 = ((id >> 7) & 7) * 64;
        int n0 = (id & 127) * 64;
        int tx = tid & 15, ty = tid >> 4;
        #pragma unroll
        for (int r = 0; r < 4; ++r) {
            int cc = r * 16 + ty;
            float4 v = *(const float4*)(rf + ((size_t)b * C_ + c0 + cc) * NC + n0 + tx * 4);
            t[tx * 4 + 0][cc] = v.x;
            t[tx * 4 + 1][cc] = v.y;
            t[tx * 4 + 2][cc] = v.z;
            t[tx * 4 + 3][cc] = v.w;
        }
        __syncthreads();
        #pragma unroll
        for (int r = 0; r < 4; ++r) {
            int n = r * 16 + ty;
            ushort4 o;
            o.x = f2bf(t[n][tx * 4 + 0]);
            o.y = f2bf(t[n][tx * 4 + 1]);
            o.z = f2bf(t[n][tx * 4 + 2]);
            o.w = f2bf(t[n][tx * 4 + 3]);
            *(ushort4*)(refT + ((size_t)b * NC + n0 + n) * C_ + c0 + tx * 4) = o;
        }
    } else {
        // ---------- seedT transpose: (B,CS,S) fp32 -> (B,S,CS) bf16 ----------
        int id = g7;                       // 0..1023
        int b = id >> 8;
        int rem = id & 255;
        int c0 = (rem >> 6) * 64;          // 0..192
        int s0 = (rem & 63) * 64;          // 0..4032
        int tx = tid & 15, ty = tid >> 4;
        #pragma unroll
        for (int r = 0; r < 4; ++r) {
            int cc = r * 16 + ty;
            float4 v = *(const float4*)(seed + ((size_t)b * CS + c0 + cc) * S_ + s0 + tx * 4);
            t[tx * 4 + 0][cc] = v.x;
            t[tx * 4 + 1][cc] = v.y;
            t[tx * 4 + 2][cc] = v.z;
            t[tx * 4 + 3][cc] = v.w;
        }
        __syncthreads();
        #pragma unroll
        for (int r = 0; r < 4; ++r) {
            int n = r * 16 + ty;
            ushort4 o;
            o.x = f2bf(t[n][tx * 4 + 0]);
            o.y = f2bf(t[n][tx * 4 + 1]);
            o.z = f2bf(t[n][tx * 4 + 2]);
            o.w = f2bf(t[n][tx * 4 + 3]);
            *(ushort4*)(seedT + ((size_t)b * S_ + s0 + n) * CS + c0 + tx * 4) = o;
        }
    }
}

// ================= K3: fused merge + gather + GEMM, 64x128 tile + 2-phase (R9) =================
// out[b](256 x 4096) = Wcomb(256x768) @ [seedT^T; gathered refT^T] + b_eff
// R10 post-mortem: LDS-free direct-MFMA regressed +25us (uncoalesced 16B
// per-lane fragment loads = 16 cache lines per fragment). LDS staging IS
// the coalescing layer -> reverted to R9's dbuf version.
// __launch_bounds__(256,2): LDS (56KB) caps residency at 2 blocks/CU
// anyway; raising the VGPR cap to the matching 2-waves/SIMD budget stops
// the allocator squeezing the 14-short8 prefetch live set (R2/R3 lesson,
// profitable direction). Fragment values and MFMA order (ks,kf,i,j)
// identical -> bit-identical output.
__global__ __launch_bounds__(256, 2) void fused_gemm_kernel(
        const unsigned short* __restrict__ Wcomb,
        const unsigned short* __restrict__ seedT,
        const unsigned short* __restrict__ refT,
        const float* __restrict__ pval,
        const int* __restrict__ pidx,
        const float* __restrict__ beff,
        float* __restrict__ out) {
    __shared__ __align__(16) unsigned short sA[2][64][72];
    __shared__ __align__(16) unsigned short sB[2][128][72];
    __shared__ int sIdx[128];
    __shared__ float sBias[64];

    int tid = threadIdx.x;
    int b = blockIdx.z;
    int m0 = blockIdx.y * 64;
    int s0 = blockIdx.x * 128;
    if (tid < 128) {
        // merge 4 chunk-partials; disjoint ascending index ranges -> (val,idx) min
        int qs = b * S_ + s0 + tid;
        float v = pval[qs * 4 + 0];
        int x = pidx[qs * 4 + 0];
        #pragma unroll
        for (int c = 1; c < 4; ++c) {
            float vv = pval[qs * 4 + c];
            int xx = pidx[qs * 4 + c];
            if (vv < v || (vv == v && xx < x)) { v = vv; x = xx; }
        }
        sIdx[tid] = x & (NC - 1);   // defensive clamp
        if (tid < 64) sBias[tid] = beff[m0 + tid];
    }

    int lane = tid & 63;
    int w = tid >> 6;
    int wm = w >> 1;                // 0..1  (M half)
    int wn = w & 1;                 // 0..1  (N half)
    int ln = lane & 15;
    int quad = lane >> 4;
    int q8 = quad * 8;

    // staging map: A 64 rows x 64k (2 short8/thread), B 128 rows x 64k (4 short8/thread)
    int mmA  = tid >> 2;            // A row 0..63
    int kk16 = (tid & 3) << 4;      // A k offset {0,16,32,48}
    int nB   = tid >> 1;            // B row 0..127
    int kk32 = (tid & 1) << 5;      // B k offset {0,32}
    const unsigned short* Arow = Wcomb + (size_t)(m0 + mmA) * KTOT + kk16;
    const unsigned short* Srow = seedT + ((size_t)b * S_ + s0 + nB) * CS + kk32;

    f32x4 acc[2][4];
    #pragma unroll
    for (int i = 0; i < 2; ++i)
        #pragma unroll
        for (int j = 0; j < 4; ++j)
            acc[i][j] = (f32x4){0.f, 0.f, 0.f, 0.f};

    short8 ra0, ra1, rb0, rb1, rb2, rb3;

    // sIdx first read by SLOAD(4) (issued in iter ks=3) -> after prologue barrier.
    #define SLOAD(PK) do {                                                         \
        int pk0 = (PK) * 64;                                                       \
        ra0 = *(const short8*)(Arow + pk0);                                        \
        ra1 = *(const short8*)(Arow + pk0 + 8);                                    \
        const unsigned short* Brow =                                               \
            (pk0 < 256) ? (Srow + pk0)                                             \
                        : (refT + ((size_t)b * NC + sIdx[nB]) * C_                 \
                           + (pk0 - 256) + kk32);                                  \
        rb0 = *(const short8*)(Brow);                                              \
        rb1 = *(const short8*)(Brow + 8);                                          \
        rb2 = *(const short8*)(Brow + 16);                                         \
        rb3 = *(const short8*)(Brow + 24);                                         \
    } while (0)

    #define SWRITE(BUF) do {                                                       \
        *(short8*)&sA[BUF][mmA][kk16]      = ra0;                                  \
        *(short8*)&sA[BUF][mmA][kk16 + 8]  = ra1;                                  \
        *(short8*)&sB[BUF][nB][kk32]       = rb0;                                  \
        *(short8*)&sB[BUF][nB][kk32 + 8]   = rb1;                                  \
        *(short8*)&sB[BUF][nB][kk32 + 16]  = rb2;                                  \
        *(short8*)&sB[BUF][nB][kk32 + 24]  = rb3;                                  \
    } while (0)

    SLOAD(0);
    SWRITE(0);
    __syncthreads();                // also covers sIdx/sBias writes

    int cur = 0;
    for (int ks = 0; ks < 12; ++ks) {
        if (ks < 11) SLOAD(ks + 1);     // prefetch next tile
        #pragma unroll
        for (int kf = 0; kf < 2; ++kf) {
            short8 af[2], bfr[4];
            #pragma unroll
            for (int i = 0; i < 2; ++i)
                af[i] = *(const short8*)&sA[cur][wm * 32 + i * 16 + ln][kf * 32 + q8];
            #pragma unroll
            for (int j = 0; j < 4; ++j)
                bfr[j] = *(const short8*)&sB[cur][wn * 64 + j * 16 + ln][kf * 32 + q8];
            #pragma unroll
            for (int i = 0; i < 2; ++i)
                #pragma unroll
                for (int j = 0; j < 4; ++j)
                    acc[i][j] = __builtin_amdgcn_mfma_f32_16x16x32_bf16(af[i], bfr[j], acc[i][j], 0, 0, 0);
        }
        if (ks < 11) {
            SWRITE(cur ^ 1);
            __syncthreads();            // ONE barrier per K-step
            cur ^= 1;
        }
    }
    #undef SLOAD
    #undef SWRITE

    #pragma unroll
    for (int i = 0; i < 2; ++i) {
        int mb = wm * 32 + i * 16 + quad * 4;
        #pragma unroll
        for (int j = 0; j < 4; ++j) {
            int col = s0 + wn * 64 + j * 16 + ln;
            #pragma unroll
            for (int r = 0; r < 4; ++r) {
                int m = mb + r;
                out[((size_t)b * CS + m0 + m) * S_ + col] = acc[i][j][r] + sBias[m];
            }
        }
    }
}

extern "C" void kernel_launch(void* const* d_in, const int* in_sizes, int n_in,
                              void* d_out, int out_size, void* d_ws, size_t ws_size,
                              hipStream_t stream) {
    const float* qxyz  = (const float*)d_in[0];
    const float* rxyz  = (const float*)d_in[1];
    const float* rfeat = (const float*)d_in[2];
    const float* seed  = (const float*)d_in[3];
    const float* Wseed = (const float*)d_in[4];
    const float* bseed = (const float*)d_in[5];
    const float* Wcat  = (const float*)d_in[6];
    const float* bcat  = (const float*)d_in[7];
    float* out = (float*)d_out;

    char* ws = (char*)d_ws;
    float* pval           = (float*)(ws);                        // 256 KB
    int* pidx             = (int*)(ws + 262144);                 // 256 KB
    float* beff           = (float*)(ws + 524288);               // 1 KB
    float4* refpk         = (float4*)(ws + 528384);              // 512 KB
    unsigned short* Wcomb = (unsigned short*)(ws + 1052672);     // 384 KB
    unsigned short* refT  = (unsigned short*)(ws + 1445888);     // 32 MB -> 35000320
    unsigned short* seedT = (unsigned short*)(ws + 35000320);    // 8 MB  -> end 43.4 MB

    hipLaunchKernelGGL(prep_kernel, dim3(288), dim3(256), 0, stream,
                       rxyz, refpk, Wcat, Wseed, Wcomb, bseed, bcat, beff);
    hipLaunchKernelGGL(mid_kernel, dim3(7168), dim3(256), 0, stream,
                       qxyz, refpk, pval, pidx, rfeat, refT, seed, seedT);
    hipLaunchKernelGGL(fused_gemm_kernel, dim3(32, 4, 4), dim3(256), 0, stream,
                       Wcomb, seedT, refT, pval, pidx, beff, out);
}